// Round 14
// baseline (80.011 us; speedup 1.0000x reference)
//
#include <hip/hip_runtime.h>
#include <hip/hip_fp16.h>

// StableTTLayer TT forward, B=131072. Round 14: two barrier domains per CU.
// R12->R13 (2x TLP, same work) gained only 13% -> wave count alone is not the
// binder; suspicion moves to the single 1024-thread barrier domain per CU
// (6 block-wide barriers, each waiting on the slowest of 16 waves, grid ==
// CU count so one slow block tails the dispatch). R14: SBLK=256 x 1024
// threads, grid=512 -> 2 co-resident blocks/CU (26.6 KB LDS each, 8 waves/
// SIMD): independent barrier domains overlap each other's phases/stragglers.
// Cost: per-CU column visits double (if phase-3 fixed cost dominates, this
// is neutral-to-worse -> declare practical roofline next round).
// All validated machinery unchanged: tables (R5), transposed MFMA (R8),
// in-place 80B-stride vbuf (R8), fused register sort (R13).
// Per-sample arithmetic is blocking-independent: absmax must be exactly
// 4.547474e-13. Scales baked: 256 * 16^4 * 256 = 2^32, undone at the end.

#define B_TOTAL 131072
#define NDIM 64
#define SBLK 256
#define THREADS 1024

typedef _Float16 half8 __attribute__((ext_vector_type(8)));
typedef _Float16 half4 __attribute__((ext_vector_type(4)));
typedef float    f32x4 __attribute__((ext_vector_type(4)));

// ---------------- K1: build tables (unchanged from R7-R13, validated) -------
__global__ __launch_bounds__(256) void build_tables(
    const float* __restrict__ core0, const float* __restrict__ mid,
    const float* __restrict__ lastc,
    half8* __restrict__ PKB, __half* __restrict__ T01, float* __restrict__ TL)
{
    const int id = blockIdx.x * 256 + threadIdx.x;
    if (id < 32768) {
        const int l  = id & 63;
        const int f  = (id >> 6) & 1;
        const int c  = (id >> 7) & 63;
        const int tt = id >> 13;
        const int q = l >> 4, li = l & 15;
        const int n = f * 16 + li;
        const int t = 1 + tt;
        half8 h;
        #pragma unroll
        for (int j = 0; j < 8; ++j) {
            const int k = q * 8 + j;
            h[j] = (_Float16)(16.0f * mid[((t * 32 + k) * 64 + c) * 32 + n]);
        }
        PKB[id] = h;
    } else if (id < 163840) {
        const int i2 = id - 32768;
        const int s = i2 & 31, c1 = (i2 >> 5) & 63, c0 = i2 >> 11;
        float acc = 0.f;
        #pragma unroll
        for (int r = 0; r < 32; ++r)
            acc = fmaf(core0[c0 * 32 + r], mid[(r * 64 + c1) * 32 + s], acc);
        T01[(c0 * 64 + c1) * 32 + s] = __float2half(acc * 256.0f);
    } else {
        const int i3 = id - 163840;
        const int c7 = i3 & 63, c6 = (i3 >> 6) & 63, r = i3 >> 12;
        const float* m5 = mid + 5 * 65536;
        float acc = 0.f;
        #pragma unroll
        for (int s = 0; s < 32; ++s)
            acc = fmaf(m5[(r * 64 + c6) * 32 + s], lastc[s * 64 + c7], acc);
        TL[(c6 * 64 + c7) * 32 + r] = acc * 256.0f;
    }
}

// ---------------- K2: main --------------------------------------------------
// dynamic smem (bytes): vbuf SBLK*80 | ord 4*SBLK*2 | colkey 2*SBLK*4 |
//                       hist 256*4 | bases 4*65*4   (~26.6 KB -> 2 blocks/CU)
__global__ __launch_bounds__(THREADS, 8) void tt_main_w2(
    const int* __restrict__ idx, const __half* __restrict__ T01,
    const half8* __restrict__ PKB, const float* __restrict__ TL,
    float* __restrict__ out)
{
    constexpr int NW  = THREADS / 64;  // 16 waves
    constexpr int CPW = 64 / NW;       // 4 columns per wave per stage
    extern __shared__ __align__(16) char smem[];
    __half*         vbuf   = reinterpret_cast<__half*>(smem);
    unsigned short* ord    = reinterpret_cast<unsigned short*>(smem + SBLK * 80);
    unsigned int*   colkey = reinterpret_cast<unsigned int*>(smem + SBLK * 88);
    unsigned int*   hist   = reinterpret_cast<unsigned int*>(smem + SBLK * 96);
    unsigned int*   bases  = hist + 256;

    const int tid  = threadIdx.x;
    const int lane = tid & 63;
    const int wv   = tid >> 6;         // 0..15
    const int li   = lane & 15;
    const int quad = lane >> 4;
    const int b0   = blockIdx.x * SBLK;

    // Phase 0+1: threads < 512 own half a sample each (1 int4, 2 sort keys)
    int k0 = 0, k1 = 0, ts0 = 0, ts1 = 0, sid = 0;
    const bool active = (tid < SBLK * 2);
    if (active) {
        sid = tid >> 1;
        const int h = tid & 1;
        const int4 iv = reinterpret_cast<const int4*>(idx)[(size_t)b0 * 2 + tid];
        const int e0 = min(max(iv.x, 0), 63), e1 = min(max(iv.y, 0), 63);
        const int e2 = min(max(iv.z, 0), 63), e3 = min(max(iv.w, 0), 63);
        // h==0: (c0,c1,key0,key1); h==1: (key2,key3,c6,c7)
        colkey[tid] = (unsigned)e0 | ((unsigned)e1 << 8) |
                      ((unsigned)e2 << 16) | ((unsigned)e3 << 24);
        k0 = h ? e0 : e2;
        k1 = h ? e1 : e3;
        ts0 = h * 2; ts1 = h * 2 + 1;
    }
    if (tid < 256) hist[tid] = 0;
    __syncthreads();

    unsigned int r0 = 0, r1 = 0;
    if (active) {
        r0 = atomicAdd(&hist[ts0 * 64 + k0], 1u);
        r1 = atomicAdd(&hist[ts1 * 64 + k1], 1u);
    }
    __syncthreads();
    if (wv < 4) {   // wave wv scans histogram wv (one lane per bin)
        const unsigned int v = hist[wv * 64 + lane];
        unsigned int inc = v;
        #pragma unroll
        for (int d = 1; d < 64; d <<= 1) {
            const unsigned int n = __shfl_up(inc, d);
            if (lane >= d) inc += n;
        }
        bases[wv * 65 + lane] = inc - v;
        if (lane == 63) bases[wv * 65 + 64] = inc;   // == SBLK
    }
    __syncthreads();
    if (active) {
        ord[ts0 * SBLK + bases[ts0 * 65 + k0] + r0] = (unsigned short)sid;
        ord[ts1 * SBLK + bases[ts1 * 65 + k1] + r1] = (unsigned short)sid;
    }

    // Phase 2: init v from T01 (8-lane groups; x256 true value); fixed slots
    {
        const int g = tid & 7, gid = tid >> 3;   // gid 0..127
        #pragma unroll
        for (int it = 0; it < SBLK / 128; ++it) {
            const int s = it * 128 + gid;
            const unsigned cc = colkey[2 * s];   // c0 | c1<<8
            const int a = cc & 255, b = (cc >> 8) & 255;
            const uint2 q = *reinterpret_cast<const uint2*>(
                T01 + (a * 64 + b) * 32 + 4 * g);
            unsigned int* vp = reinterpret_cast<unsigned int*>(vbuf + s * 40);
            vp[2 * g]     = q.x;
            vp[2 * g + 1] = q.y;
        }
    }
    __syncthreads();

    // Phase 3: 4 middle stages; 16 waves x 4 columns; A-fragment prefetch
    for (int tt = 0; tt < 4; ++tt) {
        const int cbase = wv * CPW;
        half8 A0 = PKB[((tt * 64 + cbase) * 2 + 0) * 64 + lane];
        half8 A1 = PKB[((tt * 64 + cbase) * 2 + 1) * 64 + lane];
        for (int ci = 0; ci < CPW; ++ci) {
            const int c = cbase + ci;
            half8 nA0 = A0, nA1 = A1;
            if (ci + 1 < CPW) {
                nA0 = PKB[((tt * 64 + c + 1) * 2 + 0) * 64 + lane];
                nA1 = PKB[((tt * 64 + c + 1) * 2 + 1) * 64 + lane];
            }
            const int st = (int)bases[tt * 65 + c];
            const int en = (int)bases[tt * 65 + c + 1];
            for (int p = st; p < en; p += 16) {
                const int sm = (int)ord[tt * SBLK + min(p + li, en - 1)];
                const half8 Bv = *reinterpret_cast<const half8*>(
                    vbuf + sm * 40 + quad * 8);
                f32x4 d0 = {0.f, 0.f, 0.f, 0.f}, d1 = {0.f, 0.f, 0.f, 0.f};
                d0 = __builtin_amdgcn_mfma_f32_16x16x32_f16(A0, Bv, d0, 0, 0, 0);
                d1 = __builtin_amdgcn_mfma_f32_16x16x32_f16(A1, Bv, d1, 0, 0, 0);
                // D: lane (q,li) = new_v[sample sm(li)][s_out = f*16 + q*4 + r]
                half4 w0, w1;
                #pragma unroll
                for (int r = 0; r < 4; ++r) {
                    w0[r] = (_Float16)d0[r];
                    w1[r] = (_Float16)d1[r];
                }
                __half* basep = vbuf + sm * 40 + quad * 4;
                *reinterpret_cast<half4*>(basep)      = w0;   // s_out quad*4..+3
                *reinterpret_cast<half4*>(basep + 16) = w1;   // s_out 16+quad*4..+3
            }
            A0 = nA0; A1 = nA1;
        }
        __syncthreads();
    }

    // Phase 4: final contraction vs TL (x256), 8-lane reduce, undo 2^32
    {
        const int g = tid & 7, gid = tid >> 3;
        #pragma unroll
        for (int it = 0; it < SBLK / 128; ++it) {
            const int s = it * 128 + gid;
            const unsigned cc = colkey[2 * s + 1];   // c6<<16 | c7<<24
            const int a = (cc >> 16) & 255, b = cc >> 24;
            const unsigned int* vp =
                reinterpret_cast<const unsigned int*>(vbuf + s * 40);
            const __half2 v01 = *reinterpret_cast<const __half2*>(&vp[2 * g]);
            const __half2 v23 = *reinterpret_cast<const __half2*>(&vp[2 * g + 1]);
            const float4 L = *reinterpret_cast<const float4*>(
                TL + (a * 64 + b) * 32 + 4 * g);
            float o = 0.f;
            o = fmaf(__low2float(v01),  L.x, o);
            o = fmaf(__high2float(v01), L.y, o);
            o = fmaf(__low2float(v23),  L.z, o);
            o = fmaf(__high2float(v23), L.w, o);
            o += __shfl_xor(o, 1);
            o += __shfl_xor(o, 2);
            o += __shfl_xor(o, 4);
            if (g == 0) out[b0 + s] = o * 2.3283064365386963e-10f;   // 2^-32
        }
    }
}

// ---------------- host ------------------------------------------------------
// ws: PKB 524288 B | TL 524288 B | T01 262144 B  (1310720 B total)
#define PKB_OFF 0u
#define TL_OFF  524288u
#define T01_OFF 1048576u
#define SMEM_BYTES (SBLK * 96 + 256 * 4 + 4 * 65 * 4)   // 26640 B -> 2 blocks/CU

extern "C" void kernel_launch(void* const* d_in, const int* in_sizes, int n_in,
                              void* d_out, int out_size, void* d_ws, size_t ws_size,
                              hipStream_t stream) {
    const int*   idx   = (const int*)d_in[0];    // (B, 8) int32
    const float* core0 = (const float*)d_in[1];  // (1, 64, 32)
    const float* mid   = (const float*)d_in[2];  // (6, 32, 64, 32)
    const float* lastc = (const float*)d_in[3];  // (32, 64, 1)
    float* out = (float*)d_out;

    half8*  PKB = (half8*)((char*)d_ws + PKB_OFF);
    float*  TL  = (float*)((char*)d_ws + TL_OFF);
    __half* T01 = (__half*)((char*)d_ws + T01_OFF);

    hipLaunchKernelGGL(build_tables, dim3(294912 / 256), dim3(256), 0, stream,
                       core0, mid, lastc, PKB, T01, TL);
    hipLaunchKernelGGL(tt_main_w2, dim3(B_TOTAL / SBLK), dim3(THREADS),
                       SMEM_BYTES, stream, idx, T01, PKB, TL, out);
}

// Round 15
// 76.312 us; speedup vs baseline: 1.0485x; 1.0485x over previous
//
#include <hip/hip_runtime.h>
#include <hip/hip_fp16.h>

// StableTTLayer TT forward, B=131072. Round 15: REVERT to R13 (best: 76.5us).
// R14 falsified the barrier-domain theory (2 blocks/CU doubled per-CU column
// visits -> +3.5us, matching the column-fixed-cost arm of the prediction).
// R13 is the measured optimum of the amortization x occupancy tradeoff:
// SBLK=512, 1024 threads (16 waves/CU, 4 waves/SIMD), grid=256 = all CUs,
// 64 column-visits/CU/stage.
// Lever history: traffic (R3-R5 tables @ 27TB/s gather ceiling), register-
// delivery (R7 MFMA batching), read-path indirection (R9/R10: no effect),
// amortization (R11/R12), TLP (R13 +13%), barrier domains (R14: negative).
// Residual dur_us is harness-fixed (~41us ws-poison fill + ~10us gaps +
// ~4us build) + ~20us main at its structural optimum.
// Math identical to R5-R14: absmax must be exactly 4.547474e-13.
// Scales baked: 256 * 16^4 * 256 = 2^32, undone exactly at the end.

#define B_TOTAL 131072
#define NDIM 64
#define SBLK 512
#define THREADS 1024

typedef _Float16 half8 __attribute__((ext_vector_type(8)));
typedef _Float16 half4 __attribute__((ext_vector_type(4)));
typedef float    f32x4 __attribute__((ext_vector_type(4)));

// ---------------- K1: build tables (unchanged from R7-R14, validated) -------
__global__ __launch_bounds__(256) void build_tables(
    const float* __restrict__ core0, const float* __restrict__ mid,
    const float* __restrict__ lastc,
    half8* __restrict__ PKB, __half* __restrict__ T01, float* __restrict__ TL)
{
    const int id = blockIdx.x * 256 + threadIdx.x;
    if (id < 32768) {
        const int l  = id & 63;
        const int f  = (id >> 6) & 1;
        const int c  = (id >> 7) & 63;
        const int tt = id >> 13;
        const int q = l >> 4, li = l & 15;
        const int n = f * 16 + li;
        const int t = 1 + tt;
        half8 h;
        #pragma unroll
        for (int j = 0; j < 8; ++j) {
            const int k = q * 8 + j;
            h[j] = (_Float16)(16.0f * mid[((t * 32 + k) * 64 + c) * 32 + n]);
        }
        PKB[id] = h;
    } else if (id < 163840) {
        const int i2 = id - 32768;
        const int s = i2 & 31, c1 = (i2 >> 5) & 63, c0 = i2 >> 11;
        float acc = 0.f;
        #pragma unroll
        for (int r = 0; r < 32; ++r)
            acc = fmaf(core0[c0 * 32 + r], mid[(r * 64 + c1) * 32 + s], acc);
        T01[(c0 * 64 + c1) * 32 + s] = __float2half(acc * 256.0f);
    } else {
        const int i3 = id - 163840;
        const int c7 = i3 & 63, c6 = (i3 >> 6) & 63, r = i3 >> 12;
        const float* m5 = mid + 5 * 65536;
        float acc = 0.f;
        #pragma unroll
        for (int s = 0; s < 32; ++s)
            acc = fmaf(m5[(r * 64 + c6) * 32 + s], lastc[s * 64 + c7], acc);
        TL[(c6 * 64 + c7) * 32 + r] = acc * 256.0f;
    }
}

// ---------------- K2: main --------------------------------------------------
// dynamic smem (bytes): vbuf SBLK*80 | ord 4*SBLK*2 | colkey 2*SBLK*4 |
//                       hist 256*4 | bases 4*65*4   (~50 KB)
__global__ __launch_bounds__(THREADS) void tt_main_w(
    const int* __restrict__ idx, const __half* __restrict__ T01,
    const half8* __restrict__ PKB, const float* __restrict__ TL,
    float* __restrict__ out)
{
    constexpr int NW  = THREADS / 64;  // 16 waves
    constexpr int CPW = 64 / NW;       // 4 columns per wave per stage
    extern __shared__ __align__(16) char smem[];
    __half*         vbuf   = reinterpret_cast<__half*>(smem);
    unsigned short* ord    = reinterpret_cast<unsigned short*>(smem + SBLK * 80);
    unsigned int*   colkey = reinterpret_cast<unsigned int*>(smem + SBLK * 88);
    unsigned int*   hist   = reinterpret_cast<unsigned int*>(smem + SBLK * 96);
    unsigned int*   bases  = hist + 256;

    const int tid  = threadIdx.x;
    const int lane = tid & 63;
    const int wv   = tid >> 6;         // 0..15
    const int li   = lane & 15;
    const int quad = lane >> 4;
    const int b0   = blockIdx.x * SBLK;

    // Phase 0: one coalesced int4 per thread (sample sid, half h)
    const int sid = tid >> 1, h = tid & 1;
    const int4 iv = reinterpret_cast<const int4*>(idx)[(size_t)b0 * 2 + tid];
    const int e0 = min(max(iv.x, 0), 63), e1 = min(max(iv.y, 0), 63);
    const int e2 = min(max(iv.z, 0), 63), e3 = min(max(iv.w, 0), 63);
    // h==0: e = (c0,c1,key0,key1)  ->  colkey[tid] = c0|c1<<8|k0<<16|k1<<24
    // h==1: e = (key2,key3,c6,c7)  ->  colkey[tid] = k2|k3<<8|c6<<16|c7<<24
    colkey[tid] = (unsigned)e0 | ((unsigned)e1 << 8) |
                  ((unsigned)e2 << 16) | ((unsigned)e3 << 24);
    const int k0 = h ? e0 : e2;        // this thread's two sort keys
    const int k1 = h ? e1 : e3;
    const int ts0 = h * 2, ts1 = h * 2 + 1;
    if (tid < 256) hist[tid] = 0;
    __syncthreads();

    // Phase 1: fused 4-key counting sort (2 keys per thread, in registers)
    const unsigned int r0 = atomicAdd(&hist[ts0 * 64 + k0], 1u);
    const unsigned int r1 = atomicAdd(&hist[ts1 * 64 + k1], 1u);
    __syncthreads();
    if (wv < 4) {   // wave wv scans histogram wv (one lane per bin)
        const unsigned int v = hist[wv * 64 + lane];
        unsigned int inc = v;
        #pragma unroll
        for (int d = 1; d < 64; d <<= 1) {
            const unsigned int n = __shfl_up(inc, d);
            if (lane >= d) inc += n;
        }
        bases[wv * 65 + lane] = inc - v;
        if (lane == 63) bases[wv * 65 + 64] = inc;   // == SBLK
    }
    __syncthreads();
    ord[ts0 * SBLK + bases[ts0 * 65 + k0] + r0] = (unsigned short)sid;
    ord[ts1 * SBLK + bases[ts1 * 65 + k1] + r1] = (unsigned short)sid;

    // Phase 2: init v from T01 (8-lane groups; x256 true value); fixed slots
    {
        const int g = tid & 7, gid = tid >> 3;   // gid 0..127
        #pragma unroll
        for (int it = 0; it < 4; ++it) {
            const int s = it * 128 + gid;
            const unsigned cc = colkey[2 * s];   // c0 | c1<<8 | ...
            const int a = cc & 255, b = (cc >> 8) & 255;
            const uint2 q = *reinterpret_cast<const uint2*>(
                T01 + (a * 64 + b) * 32 + 4 * g);
            unsigned int* vp = reinterpret_cast<unsigned int*>(vbuf + s * 40);
            vp[2 * g]     = q.x;
            vp[2 * g + 1] = q.y;
        }
    }
    __syncthreads();

    // Phase 3: 4 middle stages; 16 waves x 4 columns; A-fragment prefetch
    for (int tt = 0; tt < 4; ++tt) {
        const int cbase = wv * CPW;
        half8 A0 = PKB[((tt * 64 + cbase) * 2 + 0) * 64 + lane];
        half8 A1 = PKB[((tt * 64 + cbase) * 2 + 1) * 64 + lane];
        for (int ci = 0; ci < CPW; ++ci) {
            const int c = cbase + ci;
            half8 nA0 = A0, nA1 = A1;
            if (ci + 1 < CPW) {
                nA0 = PKB[((tt * 64 + c + 1) * 2 + 0) * 64 + lane];
                nA1 = PKB[((tt * 64 + c + 1) * 2 + 1) * 64 + lane];
            }
            const int st = (int)bases[tt * 65 + c];
            const int en = (int)bases[tt * 65 + c + 1];
            for (int p = st; p < en; p += 16) {
                const int sm = (int)ord[tt * SBLK + min(p + li, en - 1)];
                const half8 Bv = *reinterpret_cast<const half8*>(
                    vbuf + sm * 40 + quad * 8);
                f32x4 d0 = {0.f, 0.f, 0.f, 0.f}, d1 = {0.f, 0.f, 0.f, 0.f};
                d0 = __builtin_amdgcn_mfma_f32_16x16x32_f16(A0, Bv, d0, 0, 0, 0);
                d1 = __builtin_amdgcn_mfma_f32_16x16x32_f16(A1, Bv, d1, 0, 0, 0);
                // D: lane (q,li) = new_v[sample sm(li)][s_out = f*16 + q*4 + r]
                half4 w0, w1;
                #pragma unroll
                for (int r = 0; r < 4; ++r) {
                    w0[r] = (_Float16)d0[r];
                    w1[r] = (_Float16)d1[r];
                }
                __half* basep = vbuf + sm * 40 + quad * 4;
                *reinterpret_cast<half4*>(basep)      = w0;   // s_out quad*4..+3
                *reinterpret_cast<half4*>(basep + 16) = w1;   // s_out 16+quad*4..+3
            }
            A0 = nA0; A1 = nA1;
        }
        __syncthreads();
    }

    // Phase 4: final contraction vs TL (x256), 8-lane reduce, undo 2^32
    {
        const int g = tid & 7, gid = tid >> 3;
        #pragma unroll
        for (int it = 0; it < 4; ++it) {
            const int s = it * 128 + gid;
            const unsigned cc = colkey[2 * s + 1];   // ... | c6<<16 | c7<<24
            const int a = (cc >> 16) & 255, b = cc >> 24;
            const unsigned int* vp =
                reinterpret_cast<const unsigned int*>(vbuf + s * 40);
            const __half2 v01 = *reinterpret_cast<const __half2*>(&vp[2 * g]);
            const __half2 v23 = *reinterpret_cast<const __half2*>(&vp[2 * g + 1]);
            const float4 L = *reinterpret_cast<const float4*>(
                TL + (a * 64 + b) * 32 + 4 * g);
            float o = 0.f;
            o = fmaf(__low2float(v01),  L.x, o);
            o = fmaf(__high2float(v01), L.y, o);
            o = fmaf(__low2float(v23),  L.z, o);
            o = fmaf(__high2float(v23), L.w, o);
            o += __shfl_xor(o, 1);
            o += __shfl_xor(o, 2);
            o += __shfl_xor(o, 4);
            if (g == 0) out[b0 + s] = o * 2.3283064365386963e-10f;   // 2^-32
        }
    }
}

// ---------------- host ------------------------------------------------------
// ws: PKB 524288 B | TL 524288 B | T01 262144 B  (1310720 B total)
#define PKB_OFF 0u
#define TL_OFF  524288u
#define T01_OFF 1048576u
#define SMEM_BYTES (SBLK * 96 + 256 * 4 + 4 * 65 * 4)   // ~50.3 KB

extern "C" void kernel_launch(void* const* d_in, const int* in_sizes, int n_in,
                              void* d_out, int out_size, void* d_ws, size_t ws_size,
                              hipStream_t stream) {
    const int*   idx   = (const int*)d_in[0];    // (B, 8) int32
    const float* core0 = (const float*)d_in[1];  // (1, 64, 32)
    const float* mid   = (const float*)d_in[2];  // (6, 32, 64, 32)
    const float* lastc = (const float*)d_in[3];  // (32, 64, 1)
    float* out = (float*)d_out;

    half8*  PKB = (half8*)((char*)d_ws + PKB_OFF);
    float*  TL  = (float*)((char*)d_ws + TL_OFF);
    __half* T01 = (__half*)((char*)d_ws + T01_OFF);

    hipLaunchKernelGGL(build_tables, dim3(294912 / 256), dim3(256), 0, stream,
                       core0, mid, lastc, PKB, T01, TL);
    hipLaunchKernelGGL(tt_main_w, dim3(B_TOTAL / SBLK), dim3(THREADS),
                       SMEM_BYTES, stream, idx, T01, PKB, TL, out);
}